// Round 1
// baseline (198.193 us; speedup 1.0000x reference)
//
#include <hip/hip_runtime.h>
#include <math.h>

#define N_BOXES 10647
#define NUM_CLASSES 80
#define MAX_BOXES 20
#define IOU_T 0.1f
#define SCORE_T 0.3f

#define NMS_THREADS 1024
#define NMS_WAVES (NMS_THREADS / 64)

// Output layout (all float32, concatenated):
//   [0)            boxes copy        N_BOXES*4            = 42588
//   [42588)        scores transposed NUM_CLASSES*N_BOXES  = 851760
//   [894348)       nms_final         NUM_CLASSES*MAX_BOXES*3 = 4800
#define OUT_OFF_SCORES (N_BOXES * 4)
#define OUT_OFF_NMS (N_BOXES * 4 + NUM_CLASSES * N_BOXES)

// ---------------------------------------------------------------------------
// Kernel A: passthrough copy of boxes + transpose of scores [N,C] -> [C,N]
// ---------------------------------------------------------------------------
__global__ void copy_transpose_kernel(const float* __restrict__ boxes,
                                      const float* __restrict__ scores,
                                      float* __restrict__ out) {
    const int total = N_BOXES * 4 + NUM_CLASSES * N_BOXES;
    for (int idx = blockIdx.x * blockDim.x + threadIdx.x; idx < total;
         idx += gridDim.x * blockDim.x) {
        if (idx < N_BOXES * 4) {
            out[idx] = boxes[idx];
        } else {
            int t = idx - N_BOXES * 4;
            int c = t / N_BOXES;
            int i = t - c * N_BOXES;
            out[idx] = scores[i * NUM_CLASSES + c];
        }
    }
}

// ---------------------------------------------------------------------------
// Kernel B: greedy per-class NMS. One block per class.
// ---------------------------------------------------------------------------
__global__ __launch_bounds__(NMS_THREADS) void nms_kernel(
    const float* __restrict__ boxes, const float* __restrict__ scores,
    float* __restrict__ out) {
    __shared__ float s_score[N_BOXES];       // 42588 B
    __shared__ float red_val[NMS_WAVES];
    __shared__ int red_idx[NMS_WAVES];
    __shared__ float bc_box[4];
    __shared__ int bc_j;
    __shared__ int bc_ok;

    const int c = blockIdx.x;
    const int tid = threadIdx.x;

    // Stage masked score column into LDS: s = score >= 0.3 ? score : -inf
    for (int i = tid; i < N_BOXES; i += NMS_THREADS) {
        float v = scores[i * NUM_CLASSES + c];
        s_score[i] = (v >= SCORE_T) ? v : -INFINITY;
    }
    __syncthreads();

    const int out_base = OUT_OFF_NMS + c * MAX_BOXES * 3;
    int iter = 0;
    for (; iter < MAX_BOXES; ++iter) {
        // ---- block-wide argmax (first-occurrence tie-break, like jnp.argmax)
        float bv = -INFINITY;
        int bi = 0;
        for (int i = tid; i < N_BOXES; i += NMS_THREADS) {
            float v = s_score[i];
            if (v > bv) { bv = v; bi = i; }  // strict > keeps lowest index
        }
        #pragma unroll
        for (int off = 32; off >= 1; off >>= 1) {
            float ov = __shfl_xor(bv, off);
            int oi = __shfl_xor(bi, off);
            if (ov > bv || (ov == bv && oi < bi)) { bv = ov; bi = oi; }
        }
        const int wave = tid >> 6;
        if ((tid & 63) == 0) { red_val[wave] = bv; red_idx[wave] = bi; }
        __syncthreads();
        if (tid == 0) {
            float fv = red_val[0];
            int fi = red_idx[0];
            for (int w = 1; w < NMS_WAVES; ++w) {
                float ov = red_val[w];
                int oi = red_idx[w];
                if (ov > fv || (ov == fv && oi < fi)) { fv = ov; fi = oi; }
            }
            int ok = (fv > -INFINITY) ? 1 : 0;
            bc_j = fi;
            bc_ok = ok;
            if (ok) {
                bc_box[0] = boxes[fi * 4 + 0];
                bc_box[1] = boxes[fi * 4 + 1];
                bc_box[2] = boxes[fi * 4 + 2];
                bc_box[3] = boxes[fi * 4 + 3];
            }
            // emit row [batch, class, idx] (floats; values exact)
            out[out_base + iter * 3 + 0] = ok ? 0.0f : -1.0f;
            out[out_base + iter * 3 + 1] = ok ? (float)c : -1.0f;
            out[out_base + iter * 3 + 2] = ok ? (float)fi : -1.0f;
        }
        __syncthreads();
        if (!bc_ok) { ++iter; break; }

        // ---- suppression pass: IoU(box_j, box_i) > 0.1  (or i == j)
        // All ops individually rounded (__f*_rn) to match numpy float32 exactly.
        const float jy1 = bc_box[0], jx1 = bc_box[1];
        const float jy2 = bc_box[2], jx2 = bc_box[3];
        const float area_j =
            __fmul_rn(__fsub_rn(jy2, jy1), __fsub_rn(jx2, jx1));
        const int j = bc_j;
        for (int i = tid; i < N_BOXES; i += NMS_THREADS) {
            if (s_score[i] == -INFINITY) continue;  // already dead (j is alive)
            float4 b = ((const float4*)boxes)[i];
            float ty = fmaxf(jy1, b.x);
            float tx = fmaxf(jx1, b.y);
            float by = fminf(jy2, b.z);
            float bx = fminf(jx2, b.w);
            float dy = fmaxf(__fsub_rn(by, ty), 0.0f);
            float dx = fmaxf(__fsub_rn(bx, tx), 0.0f);
            float inter = __fmul_rn(dy, dx);
            float area_i = __fmul_rn(__fsub_rn(b.z, b.x), __fsub_rn(b.w, b.y));
            float uni = __fsub_rn(__fadd_rn(area_j, area_i), inter);
            float iou = (uni > 0.0f) ? __fdiv_rn(inter, uni) : 0.0f;
            if (iou > IOU_T || i == j) s_score[i] = -INFINITY;
        }
        __syncthreads();
    }

    // Fill any remaining slots with -1 rows.
    if (tid == 0) {
        for (; iter < MAX_BOXES; ++iter) {
            out[out_base + iter * 3 + 0] = -1.0f;
            out[out_base + iter * 3 + 1] = -1.0f;
            out[out_base + iter * 3 + 2] = -1.0f;
        }
    }
}

extern "C" void kernel_launch(void* const* d_in, const int* in_sizes, int n_in,
                              void* d_out, int out_size, void* d_ws,
                              size_t ws_size, hipStream_t stream) {
    const float* boxes = (const float*)d_in[0];   // [N,4] fp32
    const float* scores = (const float*)d_in[1];  // [N,C] fp32
    float* out = (float*)d_out;

    // Kernel A: copy + transpose (disjoint output region, independent)
    const int totalA = N_BOXES * 4 + NUM_CLASSES * N_BOXES;
    int blocksA = (totalA + 255) / 256;
    copy_transpose_kernel<<<blocksA, 256, 0, stream>>>(boxes, scores, out);

    // Kernel B: per-class NMS
    nms_kernel<<<NUM_CLASSES, NMS_THREADS, 0, stream>>>(boxes, scores, out);
}

// Round 2
// 168.410 us; speedup vs baseline: 1.1768x; 1.1768x over previous
//
#include <hip/hip_runtime.h>
#include <math.h>

#define N_BOXES 10647
#define NUM_CLASSES 80
#define MAX_BOXES 20
#define IOU_T 0.1f
#define SCORE_T 0.3f

#define NT 1024
#define NWAVES (NT / 64)
#define COPY_BLOCKS 176

// Output layout (all float32, concatenated):
//   [0)      boxes copy        N_BOXES*4               = 42588
//   [42588)  scores transposed NUM_CLASSES*N_BOXES     = 851760
//   [894348) nms_final         NUM_CLASSES*MAX_BOXES*3 = 4800
#define TOTAL_COPY (N_BOXES * 4 + NUM_CLASSES * N_BOXES)
#define OUT_OFF_NMS (N_BOXES * 4 + NUM_CLASSES * N_BOXES)

// One kernel: blocks [0,80) do per-class greedy NMS; blocks [80,256) do the
// copy + transpose concurrently (disjoint output regions).
__global__ __launch_bounds__(NT) void yolo_nms_fused(
    const float* __restrict__ boxes, const float* __restrict__ scores,
    float* __restrict__ out) {
    const int tid = threadIdx.x;

    if (blockIdx.x >= NUM_CLASSES) {
        // ---- copy boxes + transpose scores [N,C] -> [C,N] ----
        int idx = (blockIdx.x - NUM_CLASSES) * NT + tid;
        for (; idx < TOTAL_COPY; idx += COPY_BLOCKS * NT) {
            if (idx < N_BOXES * 4) {
                out[idx] = boxes[idx];
            } else {
                int t = idx - N_BOXES * 4;
                int cc = t / N_BOXES;
                int i = t - cc * N_BOXES;
                out[idx] = scores[i * NUM_CLASSES + cc];
            }
        }
        return;
    }

    // ---- per-class greedy NMS ----
    __shared__ float s_score[N_BOXES];            // 42588 B (compacted scores)
    __shared__ unsigned short s_idx[N_BOXES];     // 21294 B (compacted -> orig idx)
    __shared__ unsigned long long s_wmask[NWAVES];
    __shared__ float s_rv[NWAVES];
    __shared__ int s_rp[NWAVES];
    __shared__ float s_box[4];
    __shared__ int s_pos, s_ok;

    const int c = blockIdx.x;
    const int wave = tid >> 6;
    const int lane = tid & 63;

    // Stable compaction of candidates with score >= SCORE_T.
    // Stability (ascending original index) preserves jnp.argmax's
    // first-occurrence tie-break under exact-equal scores.
    int base = 0;
    for (int t0 = 0; t0 < N_BOXES; t0 += NT) {
        int i = t0 + tid;
        float v = (i < N_BOXES) ? scores[i * NUM_CLASSES + c] : -1.0f;
        bool keep = (v >= SCORE_T);
        unsigned long long m = __ballot(keep);
        if (lane == 0) s_wmask[wave] = m;
        __syncthreads();
        int before = 0;
        for (int w = 0; w < wave; ++w) before += __popcll(s_wmask[w]);
        before += __popcll(m & ((1ull << lane) - 1ull));
        if (keep) {
            s_score[base + before] = v;
            s_idx[base + before] = (unsigned short)i;
        }
        int tot = 0;
        for (int w = 0; w < NWAVES; ++w) tot += __popcll(s_wmask[w]);
        base += tot;
        __syncthreads();  // also protects s_wmask reuse next tile
    }
    const int M = base;

    // Initial argmax over compacted scores.
    float bv = -INFINITY;
    int bp = 0x7FFFFFFF;
    for (int i = tid; i < M; i += NT) {
        float v = s_score[i];
        if (v > bv) { bv = v; bp = i; }  // strict > keeps lowest position
    }

    const float4* boxes4 = (const float4*)boxes;
    const int out_base = OUT_OFF_NMS + c * MAX_BOXES * 3;
    int stopped = MAX_BOXES;

    for (int slot = 0; slot < MAX_BOXES; ++slot) {
        // ---- block-wide argmax reduce of (bv, bp), tie -> lower position ----
        #pragma unroll
        for (int off = 32; off >= 1; off >>= 1) {
            float ov = __shfl_xor(bv, off);
            int op = __shfl_xor(bp, off);
            if (ov > bv || (ov == bv && op < bp)) { bv = ov; bp = op; }
        }
        if (lane == 0) { s_rv[wave] = bv; s_rp[wave] = bp; }
        __syncthreads();
        if (tid == 0) {
            float fv = s_rv[0];
            int fp = s_rp[0];
            for (int w = 1; w < NWAVES; ++w) {
                float ov = s_rv[w];
                int op = s_rp[w];
                if (ov > fv || (ov == fv && op < fp)) { fv = ov; fp = op; }
            }
            int ok = (fv > -INFINITY) ? 1 : 0;
            s_ok = ok;
            s_pos = fp;
            int oi = -1;
            if (ok) {
                oi = (int)s_idx[fp];
                float4 bj = boxes4[oi];
                s_box[0] = bj.x; s_box[1] = bj.y;
                s_box[2] = bj.z; s_box[3] = bj.w;
            }
            out[out_base + slot * 3 + 0] = ok ? 0.0f : -1.0f;
            out[out_base + slot * 3 + 1] = ok ? (float)c : -1.0f;
            out[out_base + slot * 3 + 2] = ok ? (float)oi : -1.0f;
        }
        __syncthreads();
        if (!s_ok) { stopped = slot + 1; break; }
        if (slot == MAX_BOXES - 1) break;  // last slot emitted; no pass needed

        // ---- fused suppression + next argmax (single scan) ----
        // Each position i is read+written only by its own thread; the reduce's
        // barriers provide all needed ordering, so no extra barrier here.
        const float jy1 = s_box[0], jx1 = s_box[1];
        const float jy2 = s_box[2], jx2 = s_box[3];
        const float area_j = __fmul_rn(__fsub_rn(jy2, jy1), __fsub_rn(jx2, jx1));
        const int p = s_pos;
        bv = -INFINITY;
        bp = 0x7FFFFFFF;
        for (int i = tid; i < M; i += NT) {
            float v = s_score[i];
            float4 b = boxes4[s_idx[i]];  // unconditional: lets loads pipeline
            // Individually-rounded float32 ops to match numpy exactly.
            float ty = fmaxf(jy1, b.x);
            float tx = fmaxf(jx1, b.y);
            float by = fminf(jy2, b.z);
            float bx = fminf(jx2, b.w);
            float dy = fmaxf(__fsub_rn(by, ty), 0.0f);
            float dx = fmaxf(__fsub_rn(bx, tx), 0.0f);
            float inter = __fmul_rn(dy, dx);
            float area_i = __fmul_rn(__fsub_rn(b.z, b.x), __fsub_rn(b.w, b.y));
            float uni = __fsub_rn(__fadd_rn(area_j, area_i), inter);
            float iou = (uni > 0.0f) ? __fdiv_rn(inter, uni) : 0.0f;
            bool kill = (iou > IOU_T) || (i == p);
            if (kill && v != -INFINITY) {
                s_score[i] = -INFINITY;
                v = -INFINITY;
            }
            if (v > bv) { bv = v; bp = i; }
        }
    }

    // Fill remaining slots with -1 rows (only when we stopped early on !ok).
    if (tid == 0) {
        for (int slot = stopped; slot < MAX_BOXES; ++slot) {
            out[out_base + slot * 3 + 0] = -1.0f;
            out[out_base + slot * 3 + 1] = -1.0f;
            out[out_base + slot * 3 + 2] = -1.0f;
        }
    }
}

extern "C" void kernel_launch(void* const* d_in, const int* in_sizes, int n_in,
                              void* d_out, int out_size, void* d_ws,
                              size_t ws_size, hipStream_t stream) {
    const float* boxes = (const float*)d_in[0];   // [N,4] fp32
    const float* scores = (const float*)d_in[1];  // [N,C] fp32
    float* out = (float*)d_out;

    yolo_nms_fused<<<NUM_CLASSES + COPY_BLOCKS, NT, 0, stream>>>(boxes, scores,
                                                                 out);
}

// Round 3
// 155.813 us; speedup vs baseline: 1.2720x; 1.0808x over previous
//
#include <hip/hip_runtime.h>
#include <math.h>

#define N_BOXES 10647
#define NUM_CLASSES 80
#define MAX_BOXES 20
#define IOU_T 0.1f
#define SCORE_T 0.3f

#define NT 1024
#define NWAVES (NT / 64)
#define KP 11  // ceil(N_BOXES / NT): per-thread register slots
#define COPY_BLOCKS 176

// Output layout (all float32, concatenated):
//   [0)      boxes copy        N_BOXES*4               = 42588
//   [42588)  scores transposed NUM_CLASSES*N_BOXES     = 851760
//   [894348) nms_final         NUM_CLASSES*MAX_BOXES*3 = 4800
#define TOTAL_COPY (N_BOXES * 4 + NUM_CLASSES * N_BOXES)
#define OUT_OFF_NMS (N_BOXES * 4 + NUM_CLASSES * N_BOXES)

// Blocks [0,80): per-class greedy NMS. Blocks [80,256): copy + transpose
// (disjoint output regions, fully concurrent).
__global__ __launch_bounds__(NT) void yolo_nms_fused(
    const float* __restrict__ boxes, const float* __restrict__ scores,
    float* __restrict__ out) {
    const int tid = threadIdx.x;

    if (blockIdx.x >= NUM_CLASSES) {
        int idx = (blockIdx.x - NUM_CLASSES) * NT + tid;
        for (; idx < TOTAL_COPY; idx += COPY_BLOCKS * NT) {
            if (idx < N_BOXES * 4) {
                out[idx] = boxes[idx];
            } else {
                int t = idx - N_BOXES * 4;
                int cc = t / N_BOXES;
                int i = t - cc * N_BOXES;
                out[idx] = scores[i * NUM_CLASSES + cc];
            }
        }
        return;
    }

    // ---- per-class greedy NMS ----
    __shared__ float s_score[N_BOXES];         // 42588 B (compacted scores)
    __shared__ unsigned short s_idx[N_BOXES];  // 21294 B (compacted -> orig)
    __shared__ unsigned long long s_wmask[NWAVES];
    __shared__ float s_rv[NWAVES];
    __shared__ int s_rp[NWAVES];
    __shared__ float s_box[4];

    const int c = blockIdx.x;
    const int wave = tid >> 6;
    const int lane = tid & 63;
    const float4* boxes4 = (const float4*)boxes;

    // Stable compaction of candidates with score >= SCORE_T (ascending
    // original index, preserving jnp.argmax first-occurrence tie-break).
    int base = 0;
    for (int t0 = 0; t0 < N_BOXES; t0 += NT) {
        int i = t0 + tid;
        float v = (i < N_BOXES) ? scores[i * NUM_CLASSES + c] : -1.0f;
        bool keep = (v >= SCORE_T);
        unsigned long long m = __ballot(keep);
        if (lane == 0) s_wmask[wave] = m;
        __syncthreads();
        int before = 0;
        for (int w = 0; w < wave; ++w) before += __popcll(s_wmask[w]);
        before += __popcll(m & ((1ull << lane) - 1ull));
        if (keep) {
            s_score[base + before] = v;
            s_idx[base + before] = (unsigned short)i;
        }
        int tot = 0;
        for (int w = 0; w < NWAVES; ++w) tot += __popcll(s_wmask[w]);
        base += tot;
        __syncthreads();  // also protects s_wmask reuse next tile
    }
    const int M = base;

    // Prologue: pull this thread's candidates (idx, box, area) into registers
    // once; also compute the initial argmax contribution.
    float4 my_box[KP];
    float my_area[KP];
    int my_idx[KP];
    float bv = -INFINITY;
    int bp = 0x7FFFFFFF;
    #pragma unroll
    for (int k = 0; k < KP; ++k) {
        int i = tid + k * NT;
        my_idx[k] = 0;
        my_box[k] = make_float4(0.f, 0.f, 0.f, 0.f);
        my_area[k] = 0.f;
        if (i < M) {
            int oi = (int)s_idx[i];
            my_idx[k] = oi;
            float4 b = boxes4[oi];
            my_box[k] = b;
            // Same individually-rounded op order as the reference's `areas`.
            my_area[k] = __fmul_rn(__fsub_rn(b.z, b.x), __fsub_rn(b.w, b.y));
            float v = s_score[i];
            if (v > bv) { bv = v; bp = i; }  // strict > keeps lowest position
        }
    }

    const int out_base = OUT_OFF_NMS + c * MAX_BOXES * 3;
    int stopped = MAX_BOXES;

    for (int slot = 0; slot < MAX_BOXES; ++slot) {
        // ---- wave-level argmax of (bv, bp), tie -> lower position ----
        #pragma unroll
        for (int off = 32; off >= 1; off >>= 1) {
            float ov = __shfl_xor(bv, off);
            int op = __shfl_xor(bp, off);
            if (ov > bv || (ov == bv && op < bp)) { bv = ov; bp = op; }
        }
        if (lane == 0) { s_rv[wave] = bv; s_rp[wave] = bp; }
        __syncthreads();  // barrier A

        // ---- final reduce done redundantly by ALL threads (broadcast LDS
        // reads; identical deterministic result everywhere) ----
        float fv = s_rv[0];
        int fp = s_rp[0];
        #pragma unroll
        for (int w = 1; w < NWAVES; ++w) {
            float ov = s_rv[w];
            int op = s_rp[w];
            if (ov > fv || (ov == fv && op < fp)) { fv = ov; fp = op; }
        }
        if (!(fv > -INFINITY)) { stopped = slot; break; }  // uniform break

        // ---- owner thread publishes winner box from registers + emits row
        #pragma unroll
        for (int k = 0; k < KP; ++k) {
            if (fp == tid + k * NT) {
                s_box[0] = my_box[k].x;
                s_box[1] = my_box[k].y;
                s_box[2] = my_box[k].z;
                s_box[3] = my_box[k].w;
                out[out_base + slot * 3 + 0] = 0.0f;
                out[out_base + slot * 3 + 1] = (float)c;
                out[out_base + slot * 3 + 2] = (float)my_idx[k];
            }
        }
        __syncthreads();  // barrier B
        if (slot == MAX_BOXES - 1) break;  // last slot emitted; no pass needed

        // ---- fused suppression + next argmax (register boxes, LDS scores)
        const float jy1 = s_box[0], jx1 = s_box[1];
        const float jy2 = s_box[2], jx2 = s_box[3];
        // Same op order as the reference's `area1`.
        const float area_j =
            __fmul_rn(__fsub_rn(jy2, jy1), __fsub_rn(jx2, jx1));
        bv = -INFINITY;
        bp = 0x7FFFFFFF;
        #pragma unroll
        for (int k = 0; k < KP; ++k) {
            int i = tid + k * NT;
            if (i < M) {
                float v = s_score[i];
                float4 b = my_box[k];
                float ty = fmaxf(jy1, b.x);
                float tx = fmaxf(jx1, b.y);
                float by = fminf(jy2, b.z);
                float bx = fminf(jx2, b.w);
                float dy = fmaxf(__fsub_rn(by, ty), 0.0f);
                float dx = fmaxf(__fsub_rn(bx, tx), 0.0f);
                float inter = __fmul_rn(dy, dx);
                float uni =
                    __fsub_rn(__fadd_rn(area_j, my_area[k]), inter);
                float iou = (uni > 0.0f) ? __fdiv_rn(inter, uni) : 0.0f;
                bool kill = (iou > IOU_T) || (i == fp);
                if (kill && v != -INFINITY) {
                    s_score[i] = -INFINITY;
                    v = -INFINITY;
                }
                if (v > bv) { bv = v; bp = i; }
            }
        }
        // No barrier needed: each position is read/written only by its owner;
        // the next slot's barrier A orders everything else.
    }

    // Fill remaining slots (early stop) with -1 rows, in parallel.
    if (tid >= stopped && tid < MAX_BOXES) {
        out[out_base + tid * 3 + 0] = -1.0f;
        out[out_base + tid * 3 + 1] = -1.0f;
        out[out_base + tid * 3 + 2] = -1.0f;
    }
}

extern "C" void kernel_launch(void* const* d_in, const int* in_sizes, int n_in,
                              void* d_out, int out_size, void* d_ws,
                              size_t ws_size, hipStream_t stream) {
    const float* boxes = (const float*)d_in[0];   // [N,4] fp32
    const float* scores = (const float*)d_in[1];  // [N,C] fp32
    float* out = (float*)d_out;

    yolo_nms_fused<<<NUM_CLASSES + COPY_BLOCKS, NT, 0, stream>>>(boxes, scores,
                                                                 out);
}

// Round 4
// 146.003 us; speedup vs baseline: 1.3575x; 1.0672x over previous
//
#include <hip/hip_runtime.h>
#include <math.h>

#define N_BOXES 10647
#define NUM_CLASSES 80
#define MAX_BOXES 20
#define IOU_T 0.1f
#define SCORE_T 0.3f

#define NT 1024
#define NWAVES (NT / 64)
#define KP 11  // ceil(N_BOXES / NT): per-thread slots
#define COPY_BLOCKS 176

// Output layout (all float32, concatenated):
//   [0)      boxes copy        N_BOXES*4               = 42588
//   [42588)  scores transposed NUM_CLASSES*N_BOXES     = 851760
//   [894348) nms_final         NUM_CLASSES*MAX_BOXES*3 = 4800
#define TOTAL_COPY (N_BOXES * 4 + NUM_CLASSES * N_BOXES)
#define OUT_OFF_NMS (N_BOXES * 4 + NUM_CLASSES * N_BOXES)

// Blocks [0,80): per-class greedy NMS. Blocks [80,256): copy + transpose.
// launch_bounds(1024, 4): 16-wave block = 4 waves/SIMD minimum -> 128 VGPR
// cap. Without the 2nd arg the compiler capped at ~60 VGPRs and spilled the
// per-thread box/key arrays to scratch (R3: VGPR_Count=60, no speedup).
__global__ __launch_bounds__(NT, 4) void yolo_nms_fused(
    const float* __restrict__ boxes, const float* __restrict__ scores,
    float* __restrict__ out) {
    const int tid = threadIdx.x;

    if (blockIdx.x >= NUM_CLASSES) {
        int idx = (blockIdx.x - NUM_CLASSES) * NT + tid;
        for (; idx < TOTAL_COPY; idx += COPY_BLOCKS * NT) {
            if (idx < N_BOXES * 4) {
                out[idx] = boxes[idx];
            } else {
                int t = idx - N_BOXES * 4;
                int cc = t / N_BOXES;
                int i = t - cc * N_BOXES;
                out[idx] = scores[i * NUM_CLASSES + cc];
            }
        }
        return;
    }

    // ---- per-class greedy NMS ----
    __shared__ float s_score[N_BOXES];         // compaction handoff only
    __shared__ unsigned short s_idx[N_BOXES];  // compacted -> original index
    __shared__ unsigned long long s_wmask[NWAVES];
    __shared__ unsigned long long s_rk[NWAVES];
    __shared__ float s_box[4];
    __shared__ int s_wpos[MAX_BOXES];

    const int c = blockIdx.x;
    const int wave = tid >> 6;
    const int lane = tid & 63;
    const float4* boxes4 = (const float4*)boxes;

    if (tid < MAX_BOXES) s_wpos[tid] = -1;

    // Stable compaction of candidates with score >= SCORE_T (ascending
    // original index preserves jnp.argmax first-occurrence tie-break).
    int base = 0;
    for (int t0 = 0; t0 < N_BOXES; t0 += NT) {
        int i = t0 + tid;
        float v = (i < N_BOXES) ? scores[i * NUM_CLASSES + c] : -1.0f;
        bool keep = (v >= SCORE_T);
        unsigned long long m = __ballot(keep);
        if (lane == 0) s_wmask[wave] = m;
        __syncthreads();
        int before = 0;
        for (int w = 0; w < wave; ++w) before += __popcll(s_wmask[w]);
        before += __popcll(m & ((1ull << lane) - 1ull));
        if (keep) {
            s_score[base + before] = v;
            s_idx[base + before] = (unsigned short)i;
        }
        int tot = 0;
        for (int w = 0; w < NWAVES; ++w) tot += __popcll(s_wmask[w]);
        base += tot;
        __syncthreads();
    }
    const int M = base;

    // Prologue: per-thread registers. Key packs (score_bits, 0xFFFFFFFF-pos):
    // valid scores are in [0.3, 1) so float bits are positive & monotone;
    // u64 max == (max score, tie -> lowest position). Dead/empty key = 0.
    float4 my_box[KP];
    unsigned long long my_key[KP];
    unsigned long long bk = 0;
    #pragma unroll
    for (int k = 0; k < KP; ++k) {
        int i = tid + k * NT;
        my_box[k] = make_float4(0.f, 0.f, 0.f, 0.f);
        my_key[k] = 0;
        if (i < M) {
            my_box[k] = boxes4[s_idx[i]];
            float v = s_score[i];
            unsigned int vb = __float_as_uint(v);
            my_key[k] =
                ((unsigned long long)vb << 32) | (0xFFFFFFFFu - (unsigned)i);
            if (my_key[k] > bk) bk = my_key[k];
        }
    }

    const int out_base = OUT_OFF_NMS + c * MAX_BOXES * 3;

    for (int slot = 0; slot < MAX_BOXES; ++slot) {
        // ---- wave-level max of packed keys ----
        #pragma unroll
        for (int off = 32; off >= 1; off >>= 1) {
            unsigned long long o =
                (unsigned long long)__shfl_xor((long long)bk, off);
            if (o > bk) bk = o;
        }
        if (lane == 0) s_rk[wave] = bk;
        __syncthreads();  // barrier A

        // ---- final reduce, redundantly in all threads (broadcast LDS) ----
        unsigned long long r[NWAVES];
        #pragma unroll
        for (int w = 0; w < NWAVES; ++w) r[w] = s_rk[w];
        #pragma unroll
        for (int s = NWAVES / 2; s >= 1; s >>= 1)
            #pragma unroll
            for (int w = 0; w < 16; ++w)
                if (w < s && r[w + s] > r[w]) r[w] = r[w + s];
        const unsigned long long f = r[0];
        if (f == 0) break;  // uniform: no candidates left

        const int fp = (int)(0xFFFFFFFFu - (unsigned int)f);
        if (tid == 0) s_wpos[slot] = fp;
        // Owner publishes winner box from registers (no global access).
        if (tid == (fp & (NT - 1))) {
            const int wk = fp >> 10;
            #pragma unroll
            for (int k = 0; k < KP; ++k) {
                if (k == wk) {
                    s_box[0] = my_box[k].x;
                    s_box[1] = my_box[k].y;
                    s_box[2] = my_box[k].z;
                    s_box[3] = my_box[k].w;
                }
            }
        }
        __syncthreads();  // barrier B
        if (slot == MAX_BOXES - 1) break;

        // ---- fused suppression + next argmax: pure registers, zero LDS ----
        const float jy1 = s_box[0], jx1 = s_box[1];
        const float jy2 = s_box[2], jx2 = s_box[3];
        // Same individually-rounded op order as the reference.
        const float area_j =
            __fmul_rn(__fsub_rn(jy2, jy1), __fsub_rn(jx2, jx1));
        bk = 0;
        #pragma unroll
        for (int k = 0; k < KP; ++k) {
            unsigned long long kk = my_key[k];
            if (kk != 0) {
                int i = tid + k * NT;
                float4 b = my_box[k];
                float ty = fmaxf(jy1, b.x);
                float tx = fmaxf(jx1, b.y);
                float by = fminf(jy2, b.z);
                float bx = fminf(jx2, b.w);
                float dy = fmaxf(__fsub_rn(by, ty), 0.0f);
                float dx = fmaxf(__fsub_rn(bx, tx), 0.0f);
                float inter = __fmul_rn(dy, dx);
                bool kill = (i == fp);
                if (inter > 0.0f) {
                    // inter==0 => reference iou is exactly 0 (union>0 since
                    // both areas positive) => no kill; skip the divide.
                    float area_i =
                        __fmul_rn(__fsub_rn(b.z, b.x), __fsub_rn(b.w, b.y));
                    float uni = __fsub_rn(__fadd_rn(area_j, area_i), inter);
                    float iou = (uni > 0.0f) ? __fdiv_rn(inter, uni) : 0.0f;
                    kill = kill || (iou > IOU_T);
                }
                if (kill) {
                    kk = 0;
                    my_key[k] = 0;
                }
            }
            if (kk > bk) bk = kk;
        }
        // No barrier: each thread touches only its own keys; s_box/s_rk
        // accesses are ordered by barriers A/B.
    }

    // ---- emit all output rows once (keeps vmcnt drains off the hot loop) --
    __syncthreads();
    if (tid < MAX_BOXES) {
        int fp = s_wpos[tid];
        int o = out_base + tid * 3;
        if (fp >= 0) {
            out[o + 0] = 0.0f;
            out[o + 1] = (float)c;
            out[o + 2] = (float)(int)s_idx[fp];
        } else {
            out[o + 0] = -1.0f;
            out[o + 1] = -1.0f;
            out[o + 2] = -1.0f;
        }
    }
}

extern "C" void kernel_launch(void* const* d_in, const int* in_sizes, int n_in,
                              void* d_out, int out_size, void* d_ws,
                              size_t ws_size, hipStream_t stream) {
    const float* boxes = (const float*)d_in[0];   // [N,4] fp32
    const float* scores = (const float*)d_in[1];  // [N,C] fp32
    float* out = (float*)d_out;

    yolo_nms_fused<<<NUM_CLASSES + COPY_BLOCKS, NT, 0, stream>>>(boxes, scores,
                                                                 out);
}

// Round 5
// 141.256 us; speedup vs baseline: 1.4031x; 1.0336x over previous
//
#include <hip/hip_runtime.h>
#include <math.h>

#define N_BOXES 10647
#define NUM_CLASSES 80
#define MAX_BOXES 20
#define IOU_T 0.1f
#define SCORE_T 0.3f

#define NT 1024
#define NWAVES (NT / 64)
#define KP 11  // ceil(N_BOXES / NT): per-thread slots
#define COPY_BLOCKS 176

// Output layout (all float32, concatenated):
//   [0)      boxes copy        N_BOXES*4               = 42588
//   [42588)  scores transposed NUM_CLASSES*N_BOXES     = 851760
//   [894348) nms_final         NUM_CLASSES*MAX_BOXES*3 = 4800
#define TOTAL_COPY (N_BOXES * 4 + NUM_CLASSES * N_BOXES)
#define OUT_OFF_NMS (N_BOXES * 4 + NUM_CLASSES * N_BOXES)

// Blocks [0,80): per-class greedy NMS. Blocks [80,256): copy + transpose.
//
// amdgpu_waves_per_eu(4,4): hard VGPR budget = 512/4 = 128 regs. R4's
// __launch_bounds__(1024,4) was interpreted as min-BLOCKS/CU (CUDA
// semantics), clamped to 2 blocks = 8 waves/EU -> 64-reg budget -> the
// per-thread box/score arrays spilled to scratch (VGPR_Count=64, scan was
// scratch-latency-bound). Register footprint here: my_box 44 + my_score 11
// + ~40 scalars ~= 95 < 128.
__global__ __launch_bounds__(NT)
__attribute__((amdgpu_waves_per_eu(4, 4))) void yolo_nms_fused(
    const float* __restrict__ boxes, const float* __restrict__ scores,
    float* __restrict__ out) {
    const int tid = threadIdx.x;

    if (blockIdx.x >= NUM_CLASSES) {
        int idx = (blockIdx.x - NUM_CLASSES) * NT + tid;
        for (; idx < TOTAL_COPY; idx += COPY_BLOCKS * NT) {
            if (idx < N_BOXES * 4) {
                out[idx] = boxes[idx];
            } else {
                int t = idx - N_BOXES * 4;
                int cc = t / N_BOXES;
                int i = t - cc * N_BOXES;
                out[idx] = scores[i * NUM_CLASSES + cc];
            }
        }
        return;
    }

    // ---- per-class greedy NMS ----
    __shared__ float s_score[N_BOXES];         // compaction handoff only
    __shared__ unsigned short s_idx[N_BOXES];  // compacted -> original index
    __shared__ unsigned long long s_wmask[NWAVES];
    __shared__ unsigned long long s_rk[NWAVES];
    __shared__ float s_box[4];
    __shared__ int s_wpos[MAX_BOXES];

    const int c = blockIdx.x;
    const int wave = tid >> 6;
    const int lane = tid & 63;
    const float4* boxes4 = (const float4*)boxes;

    if (tid < MAX_BOXES) s_wpos[tid] = -1;

    // Stable compaction of candidates with score >= SCORE_T (ascending
    // original index preserves jnp.argmax first-occurrence tie-break).
    int base = 0;
    for (int t0 = 0; t0 < N_BOXES; t0 += NT) {
        int i = t0 + tid;
        float v = (i < N_BOXES) ? scores[i * NUM_CLASSES + c] : -1.0f;
        bool keep = (v >= SCORE_T);
        unsigned long long m = __ballot(keep);
        if (lane == 0) s_wmask[wave] = m;
        __syncthreads();
        int before = 0;
        for (int w = 0; w < wave; ++w) before += __popcll(s_wmask[w]);
        before += __popcll(m & ((1ull << lane) - 1ull));
        if (keep) {
            s_score[base + before] = v;
            s_idx[base + before] = (unsigned short)i;
        }
        int tot = 0;
        for (int w = 0; w < NWAVES; ++w) tot += __popcll(s_wmask[w]);
        base += tot;
        __syncthreads();
    }
    const int M = base;

    // Prologue: boxes + scores into registers. Dead/empty slot: score=-inf.
    float4 my_box[KP];
    float my_score[KP];
    float bv = -INFINITY;
    int bp = 0x7FFFFFFF;
    #pragma unroll
    for (int k = 0; k < KP; ++k) {
        int i = tid + k * NT;
        my_box[k] = make_float4(0.f, 0.f, 0.f, 0.f);
        my_score[k] = -INFINITY;
        if (i < M) {
            my_box[k] = boxes4[s_idx[i]];
            float v = s_score[i];
            my_score[k] = v;
            if (v > bv) { bv = v; bp = i; }  // strict >, k asc => lowest pos
        }
    }

    const int out_base = OUT_OFF_NMS + c * MAX_BOXES * 3;

    for (int slot = 0; slot < MAX_BOXES; ++slot) {
        // ---- pack (score, pos) into one u64 key: valid scores are in
        // [0.3, 1) so float bits are positive & monotone; u64 max ==
        // (max score, tie -> lowest position). No-candidate key = 0.
        unsigned long long bk = 0;
        if (bv > -INFINITY) {
            bk = ((unsigned long long)__float_as_uint(bv) << 32) |
                 (0xFFFFFFFFu - (unsigned int)bp);
        }
        // ---- wave-level max of packed keys ----
        #pragma unroll
        for (int off = 32; off >= 1; off >>= 1) {
            unsigned long long o =
                (unsigned long long)__shfl_xor((long long)bk, off);
            if (o > bk) bk = o;
        }
        if (lane == 0) s_rk[wave] = bk;
        __syncthreads();  // barrier A

        // ---- final reduce, redundantly in all threads (broadcast LDS;
        // sequential 2-reg max keeps peak VGPR pressure low) ----
        unsigned long long f = s_rk[0];
        #pragma unroll
        for (int w = 1; w < NWAVES; ++w) {
            unsigned long long o = s_rk[w];
            if (o > f) f = o;
        }
        if (f == 0) break;  // uniform: no candidates left

        const int fp = (int)(0xFFFFFFFFu - (unsigned int)f);
        if (tid == 0) s_wpos[slot] = fp;
        // Owner publishes winner box from its registers (no global access).
        if (tid == (fp & (NT - 1))) {
            const int wk = fp >> 10;
            #pragma unroll
            for (int k = 0; k < KP; ++k) {
                if (k == wk) {
                    s_box[0] = my_box[k].x;
                    s_box[1] = my_box[k].y;
                    s_box[2] = my_box[k].z;
                    s_box[3] = my_box[k].w;
                }
            }
        }
        __syncthreads();  // barrier B
        if (slot == MAX_BOXES - 1) break;

        // ---- fused suppression + next argmax: pure registers ----
        const float jy1 = s_box[0], jx1 = s_box[1];
        const float jy2 = s_box[2], jx2 = s_box[3];
        // Same individually-rounded op order as the reference.
        const float area_j =
            __fmul_rn(__fsub_rn(jy2, jy1), __fsub_rn(jx2, jx1));
        bv = -INFINITY;
        bp = 0x7FFFFFFF;
        #pragma unroll
        for (int k = 0; k < KP; ++k) {
            float v = my_score[k];
            if (v != -INFINITY) {
                int i = tid + k * NT;
                float4 b = my_box[k];
                float ty = fmaxf(jy1, b.x);
                float tx = fmaxf(jx1, b.y);
                float by = fminf(jy2, b.z);
                float bx = fminf(jx2, b.w);
                float dy = fmaxf(__fsub_rn(by, ty), 0.0f);
                float dx = fmaxf(__fsub_rn(bx, tx), 0.0f);
                float inter = __fmul_rn(dy, dx);
                bool kill = (i == fp);
                if (inter > 0.0f) {
                    // inter==0 => reference IoU is exactly 0 (union>0 since
                    // both areas positive) => no kill; skip the divide.
                    float area_i =
                        __fmul_rn(__fsub_rn(b.z, b.x), __fsub_rn(b.w, b.y));
                    float uni = __fsub_rn(__fadd_rn(area_j, area_i), inter);
                    float iou = (uni > 0.0f) ? __fdiv_rn(inter, uni) : 0.0f;
                    kill = kill || (iou > IOU_T);
                }
                if (kill) {
                    v = -INFINITY;
                    my_score[k] = -INFINITY;
                }
                if (v > bv) { bv = v; bp = i; }
            }
        }
        // No barrier: each thread touches only its own slots; s_box/s_rk
        // accesses are ordered by barriers A/B.
    }

    // ---- emit all output rows once (keeps vmcnt drains off the hot loop) --
    __syncthreads();
    if (tid < MAX_BOXES) {
        int fp = s_wpos[tid];
        int o = out_base + tid * 3;
        if (fp >= 0) {
            out[o + 0] = 0.0f;
            out[o + 1] = (float)c;
            out[o + 2] = (float)(int)s_idx[fp];
        } else {
            out[o + 0] = -1.0f;
            out[o + 1] = -1.0f;
            out[o + 2] = -1.0f;
        }
    }
}

extern "C" void kernel_launch(void* const* d_in, const int* in_sizes, int n_in,
                              void* d_out, int out_size, void* d_ws,
                              size_t ws_size, hipStream_t stream) {
    const float* boxes = (const float*)d_in[0];   // [N,4] fp32
    const float* scores = (const float*)d_in[1];  // [N,C] fp32
    float* out = (float*)d_out;

    yolo_nms_fused<<<NUM_CLASSES + COPY_BLOCKS, NT, 0, stream>>>(boxes, scores,
                                                                 out);
}

// Round 6
// 141.067 us; speedup vs baseline: 1.4050x; 1.0013x over previous
//
#include <hip/hip_runtime.h>
#include <math.h>

#define N_BOXES 10647
#define NUM_CLASSES 80
#define MAX_BOXES 20
#define IOU_T 0.1f
#define SCORE_T 0.3f

#define NT 1024
#define NWAVES (NT / 64)
#define KP 11  // ceil(N_BOXES / NT): per-thread slots
#define COPY_BLOCKS 176

// Output layout (all float32, concatenated):
//   [0)      boxes copy        N_BOXES*4               = 42588
//   [42588)  scores transposed NUM_CLASSES*N_BOXES     = 851760
//   [894348) nms_final         NUM_CLASSES*MAX_BOXES*3 = 4800
#define TOTAL_COPY (N_BOXES * 4 + NUM_CLASSES * N_BOXES)
#define OUT_OFF_NMS (N_BOXES * 4 + NUM_CLASSES * N_BOXES)

// Blocks [0,80): per-class greedy NMS. Blocks [80,256): copy + transpose.
//
// REGISTER-RESIDENCY NOTE (R3-R5 post-mortems): a private float4[11] array
// (176 B = 44 VGPRs) exceeds LLVM PromoteAlloca's per-alloca limit, so it
// was silently placed in scratch for three rounds (VGPR_Count 56-64, scan
// scratch-latency-bound at ~80 us). Splitting into four float[11] arrays
// (11 regs each, under the limit, same as my_score which DID promote) lets
// every array live in registers. waves_per_eu(4,4) keeps the VGPR budget at
// 512/4 = 128 so the ~95-reg total fits without spill.
__global__ __launch_bounds__(NT)
__attribute__((amdgpu_waves_per_eu(4, 4))) void yolo_nms_fused(
    const float* __restrict__ boxes, const float* __restrict__ scores,
    float* __restrict__ out) {
    const int tid = threadIdx.x;

    if (blockIdx.x >= NUM_CLASSES) {
        int idx = (blockIdx.x - NUM_CLASSES) * NT + tid;
        for (; idx < TOTAL_COPY; idx += COPY_BLOCKS * NT) {
            if (idx < N_BOXES * 4) {
                out[idx] = boxes[idx];
            } else {
                int t = idx - N_BOXES * 4;
                int cc = t / N_BOXES;
                int i = t - cc * N_BOXES;
                out[idx] = scores[i * NUM_CLASSES + cc];
            }
        }
        return;
    }

    // ---- per-class greedy NMS ----
    __shared__ float s_score[N_BOXES];         // compaction handoff only
    __shared__ unsigned short s_idx[N_BOXES];  // compacted -> original index
    __shared__ unsigned long long s_wmask[NWAVES];
    __shared__ unsigned long long s_rk[NWAVES];
    __shared__ float s_box[4];
    __shared__ int s_wpos[MAX_BOXES];

    const int c = blockIdx.x;
    const int wave = tid >> 6;
    const int lane = tid & 63;
    const float4* boxes4 = (const float4*)boxes;

    if (tid < MAX_BOXES) s_wpos[tid] = -1;

    // Stable compaction of candidates with score >= SCORE_T (ascending
    // original index preserves jnp.argmax first-occurrence tie-break).
    int base = 0;
    for (int t0 = 0; t0 < N_BOXES; t0 += NT) {
        int i = t0 + tid;
        float v = (i < N_BOXES) ? scores[i * NUM_CLASSES + c] : -1.0f;
        bool keep = (v >= SCORE_T);
        unsigned long long m = __ballot(keep);
        if (lane == 0) s_wmask[wave] = m;
        __syncthreads();
        int before = 0;
        for (int w = 0; w < wave; ++w) before += __popcll(s_wmask[w]);
        before += __popcll(m & ((1ull << lane) - 1ull));
        if (keep) {
            s_score[base + before] = v;
            s_idx[base + before] = (unsigned short)i;
        }
        int tot = 0;
        for (int w = 0; w < NWAVES; ++w) tot += __popcll(s_wmask[w]);
        base += tot;
        __syncthreads();
    }
    const int M = base;

    // Prologue: boxes + scores into registers (four scalar arrays so each
    // alloca is small enough for PromoteAlloca). Dead/empty: score=-inf.
    float my_y1[KP], my_x1[KP], my_y2[KP], my_x2[KP];
    float my_score[KP];
    float bv = -INFINITY;
    int bp = 0x7FFFFFFF;
    #pragma unroll
    for (int k = 0; k < KP; ++k) {
        int i = tid + k * NT;
        my_y1[k] = 0.f;
        my_x1[k] = 0.f;
        my_y2[k] = 0.f;
        my_x2[k] = 0.f;
        my_score[k] = -INFINITY;
        if (i < M) {
            float4 b = boxes4[s_idx[i]];
            my_y1[k] = b.x;
            my_x1[k] = b.y;
            my_y2[k] = b.z;
            my_x2[k] = b.w;
            float v = s_score[i];
            my_score[k] = v;
            if (v > bv) { bv = v; bp = i; }  // strict >, k asc => lowest pos
        }
    }

    const int out_base = OUT_OFF_NMS + c * MAX_BOXES * 3;

    for (int slot = 0; slot < MAX_BOXES; ++slot) {
        // ---- pack (score, pos) into one u64 key: valid scores are in
        // [0.3, 1) so float bits are positive & monotone; u64 max ==
        // (max score, tie -> lowest position). No-candidate key = 0.
        unsigned long long bk = 0;
        if (bv > -INFINITY) {
            bk = ((unsigned long long)__float_as_uint(bv) << 32) |
                 (0xFFFFFFFFu - (unsigned int)bp);
        }
        // ---- wave-level max of packed keys ----
        #pragma unroll
        for (int off = 32; off >= 1; off >>= 1) {
            unsigned long long o =
                (unsigned long long)__shfl_xor((long long)bk, off);
            if (o > bk) bk = o;
        }
        if (lane == 0) s_rk[wave] = bk;
        __syncthreads();  // barrier A

        // ---- final reduce, redundantly in all threads (broadcast LDS) ----
        unsigned long long f = s_rk[0];
        #pragma unroll
        for (int w = 1; w < NWAVES; ++w) {
            unsigned long long o = s_rk[w];
            if (o > f) f = o;
        }
        if (f == 0) break;  // uniform: no candidates left

        const int fp = (int)(0xFFFFFFFFu - (unsigned int)f);
        if (tid == 0) s_wpos[slot] = fp;
        // Owner publishes winner box from its registers (no global access).
        if (tid == (fp & (NT - 1))) {
            const int wk = fp >> 10;
            #pragma unroll
            for (int k = 0; k < KP; ++k) {
                if (k == wk) {
                    s_box[0] = my_y1[k];
                    s_box[1] = my_x1[k];
                    s_box[2] = my_y2[k];
                    s_box[3] = my_x2[k];
                }
            }
        }
        __syncthreads();  // barrier B
        if (slot == MAX_BOXES - 1) break;

        // ---- fused suppression + next argmax: pure registers ----
        const float jy1 = s_box[0], jx1 = s_box[1];
        const float jy2 = s_box[2], jx2 = s_box[3];
        // Same individually-rounded op order as the reference.
        const float area_j =
            __fmul_rn(__fsub_rn(jy2, jy1), __fsub_rn(jx2, jx1));
        bv = -INFINITY;
        bp = 0x7FFFFFFF;
        #pragma unroll
        for (int k = 0; k < KP; ++k) {
            float v = my_score[k];
            if (v != -INFINITY) {
                int i = tid + k * NT;
                float ty = fmaxf(jy1, my_y1[k]);
                float tx = fmaxf(jx1, my_x1[k]);
                float by = fminf(jy2, my_y2[k]);
                float bx = fminf(jx2, my_x2[k]);
                float dy = fmaxf(__fsub_rn(by, ty), 0.0f);
                float dx = fmaxf(__fsub_rn(bx, tx), 0.0f);
                float inter = __fmul_rn(dy, dx);
                bool kill = (i == fp);
                if (inter > 0.0f) {
                    // inter==0 => reference IoU is exactly 0 (union>0 since
                    // both areas positive) => no kill; skip the divide.
                    float area_i = __fmul_rn(__fsub_rn(my_y2[k], my_y1[k]),
                                             __fsub_rn(my_x2[k], my_x1[k]));
                    float uni = __fsub_rn(__fadd_rn(area_j, area_i), inter);
                    float iou = (uni > 0.0f) ? __fdiv_rn(inter, uni) : 0.0f;
                    kill = kill || (iou > IOU_T);
                }
                if (kill) {
                    v = -INFINITY;
                    my_score[k] = -INFINITY;
                }
                if (v > bv) { bv = v; bp = i; }
            }
        }
        // No barrier: each thread touches only its own slots; s_box/s_rk
        // accesses are ordered by barriers A/B.
    }

    // ---- emit all output rows once (keeps vmcnt drains off the hot loop) --
    __syncthreads();
    if (tid < MAX_BOXES) {
        int fp = s_wpos[tid];
        int o = out_base + tid * 3;
        if (fp >= 0) {
            out[o + 0] = 0.0f;
            out[o + 1] = (float)c;
            out[o + 2] = (float)(int)s_idx[fp];
        } else {
            out[o + 0] = -1.0f;
            out[o + 1] = -1.0f;
            out[o + 2] = -1.0f;
        }
    }
}

extern "C" void kernel_launch(void* const* d_in, const int* in_sizes, int n_in,
                              void* d_out, int out_size, void* d_ws,
                              size_t ws_size, hipStream_t stream) {
    const float* boxes = (const float*)d_in[0];   // [N,4] fp32
    const float* scores = (const float*)d_in[1];  // [N,C] fp32
    float* out = (float*)d_out;

    yolo_nms_fused<<<NUM_CLASSES + COPY_BLOCKS, NT, 0, stream>>>(boxes, scores,
                                                                 out);
}

// Round 7
// 140.499 us; speedup vs baseline: 1.4106x; 1.0040x over previous
//
#include <hip/hip_runtime.h>
#include <math.h>

#define N_BOXES 10647
#define NUM_CLASSES 80
#define MAX_BOXES 20
#define IOU_T 0.1f
#define SCORE_T 0.3f

#define NT 1024
#define NWAVES (NT / 64)
#define KP 11  // ceil(N_BOXES / NT): per-thread slots
#define COPY_BLOCKS 176

// Output layout (all float32, concatenated):
//   [0)      boxes copy        N_BOXES*4               = 42588
//   [42588)  scores transposed NUM_CLASSES*N_BOXES     = 851760
//   [894348) nms_final         NUM_CLASSES*MAX_BOXES*3 = 4800
#define TOTAL_COPY (N_BOXES * 4 + NUM_CLASSES * N_BOXES)
#define OUT_OFF_NMS (N_BOXES * 4 + NUM_CLASSES * N_BOXES)

// REGISTER-RESIDENCY NOTE (R3-R6 post-mortems): private ARRAYS (float4[11],
// and even four float[11]) never got promoted to registers -- SROA runs
// before the k-loops are unrolled, sees variable indices, and leaves the
// allocas in scratch (VGPR_Count stuck at 56-64, scan latency-bound on
// scratch reloads, VALUBusy ~19%). Fix: NO arrays at all -- 11 sets of
// individually named scalars, macro-expanded. These are SSA values from the
// front end; there is no alloca to mis-handle.
#define FOR_K(OP) OP(0) OP(1) OP(2) OP(3) OP(4) OP(5) OP(6) OP(7) OP(8) OP(9) OP(10)

// Blocks [0,80): per-class greedy NMS. Blocks [80,256): copy + transpose.
// waves_per_eu(4,4): VGPR budget 512/4 = 128; footprint ~55 named scalars
// + ~30 temps fits without spill.
__global__ __launch_bounds__(NT)
__attribute__((amdgpu_waves_per_eu(4, 4))) void yolo_nms_fused(
    const float* __restrict__ boxes, const float* __restrict__ scores,
    float* __restrict__ out) {
    const int tid = threadIdx.x;

    if (blockIdx.x >= NUM_CLASSES) {
        int idx = (blockIdx.x - NUM_CLASSES) * NT + tid;
        for (; idx < TOTAL_COPY; idx += COPY_BLOCKS * NT) {
            if (idx < N_BOXES * 4) {
                out[idx] = boxes[idx];
            } else {
                int t = idx - N_BOXES * 4;
                int cc = t / N_BOXES;
                int i = t - cc * N_BOXES;
                out[idx] = scores[i * NUM_CLASSES + cc];
            }
        }
        return;
    }

    // ---- per-class greedy NMS ----
    __shared__ float s_score[N_BOXES];         // compaction handoff only
    __shared__ unsigned short s_idx[N_BOXES];  // compacted -> original index
    __shared__ unsigned long long s_wmask[NWAVES];
    __shared__ unsigned long long s_rk[NWAVES];
    __shared__ float s_box[4];
    __shared__ int s_wpos[MAX_BOXES];

    const int c = blockIdx.x;
    const int wave = tid >> 6;
    const int lane = tid & 63;
    const float4* boxes4 = (const float4*)boxes;

    if (tid < MAX_BOXES) s_wpos[tid] = -1;

    // Stable compaction of candidates with score >= SCORE_T (ascending
    // original index preserves jnp.argmax first-occurrence tie-break).
    int base = 0;
    for (int t0 = 0; t0 < N_BOXES; t0 += NT) {
        int i = t0 + tid;
        float v = (i < N_BOXES) ? scores[i * NUM_CLASSES + c] : -1.0f;
        bool keep = (v >= SCORE_T);
        unsigned long long m = __ballot(keep);
        if (lane == 0) s_wmask[wave] = m;
        __syncthreads();
        int before = 0;
        for (int w = 0; w < wave; ++w) before += __popcll(s_wmask[w]);
        before += __popcll(m & ((1ull << lane) - 1ull));
        if (keep) {
            s_score[base + before] = v;
            s_idx[base + before] = (unsigned short)i;
        }
        int tot = 0;
        for (int w = 0; w < NWAVES; ++w) tot += __popcll(s_wmask[w]);
        base += tot;
        __syncthreads();
    }
    const int M = base;

    // ---- named per-slot scalars (no allocas) ----
#define DECL_K(k) float y1_##k, x1_##k, y2_##k, x2_##k, sc_##k;
    FOR_K(DECL_K)
#undef DECL_K

    float bv = -INFINITY;
    int bp = 0x7FFFFFFF;
#define LOAD_K(k)                                          \
    {                                                      \
        int i = tid + (k)*NT;                              \
        y1_##k = 0.f; x1_##k = 0.f;                        \
        y2_##k = 0.f; x2_##k = 0.f;                        \
        sc_##k = -INFINITY;                                \
        if (i < M) {                                       \
            float4 b = boxes4[s_idx[i]];                   \
            y1_##k = b.x; x1_##k = b.y;                    \
            y2_##k = b.z; x2_##k = b.w;                    \
            float v = s_score[i];                          \
            sc_##k = v;                                    \
            if (v > bv) { bv = v; bp = i; }                \
        }                                                  \
    }
    FOR_K(LOAD_K)
#undef LOAD_K

    const int out_base = OUT_OFF_NMS + c * MAX_BOXES * 3;

    for (int slot = 0; slot < MAX_BOXES; ++slot) {
        // Pack (score, pos) into one u64 key: valid scores in [0.3, 1) so
        // float bits are positive & monotone; u64 max == (max score,
        // tie -> lowest position). No-candidate key = 0.
        unsigned long long bk = 0;
        if (bv > -INFINITY) {
            bk = ((unsigned long long)__float_as_uint(bv) << 32) |
                 (0xFFFFFFFFu - (unsigned int)bp);
        }
        // ---- wave-level max of packed keys ----
        #pragma unroll
        for (int off = 32; off >= 1; off >>= 1) {
            unsigned long long o =
                (unsigned long long)__shfl_xor((long long)bk, off);
            if (o > bk) bk = o;
        }
        if (lane == 0) s_rk[wave] = bk;
        __syncthreads();  // barrier A

        // ---- final reduce, redundantly in all threads (broadcast LDS) ----
        unsigned long long f = s_rk[0];
        #pragma unroll
        for (int w = 1; w < NWAVES; ++w) {
            unsigned long long o = s_rk[w];
            if (o > f) f = o;
        }
        if (f == 0) break;  // uniform: no candidates left

        const int fp = (int)(0xFFFFFFFFu - (unsigned int)f);
        if (tid == 0) s_wpos[slot] = fp;
        // Owner publishes winner box from its registers (no global access).
        if (tid == (fp & (NT - 1))) {
            const int wk = fp >> 10;
#define PUB_K(k)                                           \
            if (wk == (k)) {                               \
                s_box[0] = y1_##k; s_box[1] = x1_##k;      \
                s_box[2] = y2_##k; s_box[3] = x2_##k;      \
            }
            FOR_K(PUB_K)
#undef PUB_K
        }
        __syncthreads();  // barrier B
        if (slot == MAX_BOXES - 1) break;

        // ---- fused suppression + next argmax: pure registers ----
        const float jy1 = s_box[0], jx1 = s_box[1];
        const float jy2 = s_box[2], jx2 = s_box[3];
        // Same individually-rounded op order as the reference.
        const float area_j =
            __fmul_rn(__fsub_rn(jy2, jy1), __fsub_rn(jx2, jx1));
        bv = -INFINITY;
        bp = 0x7FFFFFFF;
#define SCAN_K(k)                                                        \
        {                                                                \
            float v = sc_##k;                                            \
            if (v != -INFINITY) {                                        \
                int i = tid + (k)*NT;                                    \
                float ty = fmaxf(jy1, y1_##k);                           \
                float tx = fmaxf(jx1, x1_##k);                           \
                float by = fminf(jy2, y2_##k);                           \
                float bx = fminf(jx2, x2_##k);                           \
                float dy = fmaxf(__fsub_rn(by, ty), 0.0f);               \
                float dx = fmaxf(__fsub_rn(bx, tx), 0.0f);               \
                float inter = __fmul_rn(dy, dx);                         \
                bool kill = (i == fp);                                   \
                if (inter > 0.0f) {                                      \
                    float area_i =                                       \
                        __fmul_rn(__fsub_rn(y2_##k, y1_##k),             \
                                  __fsub_rn(x2_##k, x1_##k));            \
                    float uni =                                          \
                        __fsub_rn(__fadd_rn(area_j, area_i), inter);     \
                    float iou =                                          \
                        (uni > 0.0f) ? __fdiv_rn(inter, uni) : 0.0f;     \
                    kill = kill || (iou > IOU_T);                        \
                }                                                        \
                if (kill) { v = -INFINITY; sc_##k = -INFINITY; }         \
                if (v > bv) { bv = v; bp = i; }                          \
            }                                                            \
        }
        FOR_K(SCAN_K)
#undef SCAN_K
        // No barrier: each thread touches only its own scalars; s_box/s_rk
        // accesses are ordered by barriers A/B.
    }

    // ---- emit all output rows once (keeps vmcnt drains off the hot loop) --
    __syncthreads();
    if (tid < MAX_BOXES) {
        int fp = s_wpos[tid];
        int o = out_base + tid * 3;
        if (fp >= 0) {
            out[o + 0] = 0.0f;
            out[o + 1] = (float)c;
            out[o + 2] = (float)(int)s_idx[fp];
        } else {
            out[o + 0] = -1.0f;
            out[o + 1] = -1.0f;
            out[o + 2] = -1.0f;
        }
    }
}

extern "C" void kernel_launch(void* const* d_in, const int* in_sizes, int n_in,
                              void* d_out, int out_size, void* d_ws,
                              size_t ws_size, hipStream_t stream) {
    const float* boxes = (const float*)d_in[0];   // [N,4] fp32
    const float* scores = (const float*)d_in[1];  // [N,C] fp32
    float* out = (float*)d_out;

    yolo_nms_fused<<<NUM_CLASSES + COPY_BLOCKS, NT, 0, stream>>>(boxes, scores,
                                                                 out);
}